// Round 8
// baseline (915.126 us; speedup 1.0000x reference)
//
#include <hip/hip_runtime.h>
#include <hip/hip_bf16.h>

typedef __attribute__((ext_vector_type(8))) short bf16x8;
typedef __attribute__((ext_vector_type(16))) float f32x16;
typedef __attribute__((ext_vector_type(2))) float f32x2;

#define DEVFN __device__ __forceinline__

constexpr int NFEAT = 32, NLAYER = 8, HID = 256;
constexpr int MROW = 32;   // rows per block -> LDS 39KB -> >=3 blocks/CU
constexpr int HS  = 264;   // h/t LDS stride (bf16 elements), 16B-aligned
constexpr int MXS = 40;    // mx LDS stride
constexpr int XS  = 33;    // x LDS stride (floats)
constexpr int WIN_E  = 2 * 256 * 16;    // 8192
constexpr int WH_E   = 16 * 256 * 16;   // 65536
constexpr int WOUT_E = 16 * 512 * 16;   // 131072
constexpr int LAYER_E = WIN_E + 4 * WH_E + WOUT_E;  // 401408 bf16 elems
constexpr size_t WT_BYTES = (size_t)LAYER_E * NLAYER * 2;  // 6422528
constexpr size_t CPERM_OFF = WT_BYTES + (size_t)NLAYER * 512 * 4 + 4;  // bo_t + sld
constexpr size_t WS_NEEDED = CPERM_OFF + (size_t)NLAYER * 32 * 4;

constexpr float MIN_BIN = 1e-4f, MIN_SLOPE = 1e-4f;
constexpr float SOFTPLUS_OFF = 0.5411666f;           // log(expm1(1 - MIN_SLOPE))
constexpr float WSCALE = 20.0f - 8.0f * MIN_BIN;     // (RMAX-RMIN) - K*MIN_BIN

DEVFN unsigned short bf16r(float f) {              // fp32 -> bf16, RNE
    unsigned u = __float_as_uint(f);
    u += 0x7fffu + ((u >> 16) & 1u);
    return (unsigned short)(u >> 16);
}
#if defined(__gfx950__) && __has_builtin(__builtin_amdgcn_cvt_pk_bf16_f32)
DEVFN unsigned pack2(float a, float b) {
    auto r = __builtin_amdgcn_cvt_pk_bf16_f32(a, b);
    return __builtin_bit_cast(unsigned, r);
}
#else
DEVFN unsigned pack2(float a, float b) {
    return (unsigned)bf16r(a) | ((unsigned)bf16r(b) << 16);
}
#endif
DEVFN float bflo(unsigned v) { return __uint_as_float(v << 16); }
DEVFN float bfhi(unsigned v) { return __uint_as_float(v & 0xffff0000u); }
DEVFN float frcp(float x) { return __builtin_amdgcn_rcpf(x); }
DEVFN f32x2 vmax0(f32x2 v) {
#if __has_builtin(__builtin_elementwise_max)
    return __builtin_elementwise_max(v, (f32x2){0.f, 0.f});
#else
    return (f32x2){fmaxf(v.x, 0.f), fmaxf(v.y, 0.f)};
#endif
}

// ---------------- prep kernel: bf16 transposed weight tiles in ws ----------------
// wt layout per matrix: [kstep][n][16kk] with element = W[k=kstep*16+kk][n]
__global__ __launch_bounds__(256) void prep_kernel(
    const float* __restrict__ Win, const float* __restrict__ W1a, const float* __restrict__ W1b,
    const float* __restrict__ W2a, const float* __restrict__ W2b, const float* __restrict__ Wout,
    const float* __restrict__ bout, const float* __restrict__ scS,
    const int* __restrict__ perms,
    short* __restrict__ wt, float* __restrict__ bo_t, float* __restrict__ sld,
    int* __restrict__ cperm)
{
    __shared__ float lb[16 * 800];
    const int b = blockIdx.x, t = threadIdx.x;
    if (b < 16) {                       // W_in: (L,32,256), k-dim = 32 -> 2 ksteps
        int l = b >> 1, ks = b & 1;
        const float* src = Win + l * 32 * 256 + ks * 16 * 256;
#pragma unroll
        for (int i = 0; i < 16; i++) { int idx = t + i * 256; lb[idx] = src[idx]; }
        __syncthreads();
        short* dst = wt + (size_t)l * LAYER_E + ks * 4096;
#pragma unroll
        for (int i = 0; i < 16; i++) {
            int o = t + i * 256; int n = o >> 4, kk = o & 15;
            dst[o] = (short)bf16r(lb[kk * 256 + n]);
        }
    } else if (b < 528) {               // W1a/W1b/W2a/W2b: 256x256, 16 ksteps each
        int id = b - 16; int l = id >> 6, mat = (id >> 4) & 3, ks = id & 15;
        const float* mats[4] = {W1a, W1b, W2a, W2b};
        const float* src = mats[mat] + l * 65536 + ks * 16 * 256;
#pragma unroll
        for (int i = 0; i < 16; i++) { int idx = t + i * 256; lb[idx] = src[idx]; }
        __syncthreads();
        short* dst = wt + (size_t)l * LAYER_E + WIN_E + mat * WH_E + ks * 4096;
#pragma unroll
        for (int i = 0; i < 16; i++) {
            int o = t + i * 256; int n = o >> 4, kk = o & 15;
            dst[o] = (short)bf16r(lb[kk * 256 + n]);
        }
    } else if (b < 656) {               // W_out: trim to unmasked cols, pad 25->32
        int id = b - 528; int l = id >> 4, ks = id & 15; int par = l & 1;
        const float* src = Wout + (size_t)l * 256 * 800 + ks * 16 * 800;
        for (int k = 0; k < 16; k++)
            for (int c = t; c < 800; c += 256) lb[k * 800 + c] = src[k * 800 + c];
        __syncthreads();
        short* dst = wt + (size_t)l * LAYER_E + WIN_E + 4 * WH_E + ks * 8192;
#pragma unroll
        for (int i = 0; i < 32; i++) {
            int o = t + i * 256; int c = o >> 4, kk = o & 15;
            int u = c >> 5, p = c & 31;
            float v = (p < 25) ? lb[kk * 800 + (2 * u + par) * 25 + p] : 0.0f;
            dst[o] = (short)bf16r(v);
        }
    } else {                            // trimmed b_out + scale-logdet + composed perms
        if (t == 0) {                   // C_l = C_{l-1} o P_l  (frame-l feature -> storage col)
            for (int j = 0; j < 32; j++) cperm[j] = perms[j];
            for (int l = 1; l < NLAYER; l++)
                for (int j = 0; j < 32; j++)
                    cperm[l * 32 + j] = cperm[(l - 1) * 32 + perms[l * 32 + j]];
        }
#pragma unroll
        for (int i = 0; i < 16; i++) {
            int idx = t + i * 256;                    // 8 layers * 512
            int l = idx >> 9, c = idx & 511, u = c >> 5, p = c & 31;
            bo_t[idx] = (p < 25) ? bout[l * 800 + (2 * u + (l & 1)) * 25 + p] : 0.0f;
        }
        lb[t] = logf(fabsf(scS[t]));                  // 8*32 = 256 values
        __syncthreads();
        for (int s = 128; s > 0; s >>= 1) { if (t < s) lb[t] += lb[t + s]; __syncthreads(); }
        if (t == 0) *sld = lb[0];
    }
}

// ---------------- flipped GEMM (M=32): A = weights, B = activations (LDS) ----
// Each wave owns 64 cols = 2x 32-col subtiles; ONE MFMA covers all 32 rows.
// Ring is [4][2] (D<=4, NSUB=2) = 32 VGPR; prefA hoisted before the barrier.
template<int D>
DEVFN void prefA(const short* __restrict__ wt, int ntot, int nbase, bf16x8 (&a)[4][2])
{
    const int lane = threadIdx.x & 63;
    const bf16x8* __restrict__ w8 = (const bf16x8*)wt;
    const int wb = (nbase + (lane & 31)) * 2 + (lane >> 5);
    const int krow = ntot * 2;                        // bf16x8 units per kstep row
#pragma unroll
    for (int p = 0; p < D; p++) {
        a[p][0] = w8[(size_t)p * krow + wb];
        a[p][1] = w8[(size_t)p * krow + wb + 64];     // +32 cols
    }
}

template<int KSTEPS, int D>
DEVFN void gemm_run(const short* __restrict__ wt, int ntot, int nbase,
                    const unsigned short* __restrict__ B, int bs,
                    bf16x8 (&a)[4][2], f32x16 (&acc)[2])
{
    const int lane = threadIdx.x & 63;
    const int l31 = lane & 31, l5 = lane >> 5;
    const bf16x8* __restrict__ w8 = (const bf16x8*)wt;
    const int wb = (nbase + l31) * 2 + l5;
    const int krow = ntot * 2;
    const unsigned short* bp = B + l31 * bs + l5 * 8;
#pragma unroll
    for (int k = 0; k < KSTEPS; k++) {
        bf16x8 b0 = *(const bf16x8*)(bp + k * 16);
        acc[0] = __builtin_amdgcn_mfma_f32_32x32x16_bf16(a[k % D][0], b0, acc[0], 0, 0, 0);
        acc[1] = __builtin_amdgcn_mfma_f32_32x32x16_bf16(a[k % D][1], b0, acc[1], 0, 0, 0);
        if (k + D < KSTEPS) {
            a[k % D][0] = w8[(size_t)(k + D) * krow + wb];
            a[k % D][1] = w8[(size_t)(k + D) * krow + wb + 64];
        }
    }
}

// acc init from bias; D-layout row(param) = (reg&3)+8*(reg>>2)+4*(lane>>5)
DEVFN void binit(f32x16& a, const float* __restrict__ bias)
{
    const int q = (threadIdx.x >> 5) & 1;
    const float* bp = bias + 4 * q;
#pragma unroll
    for (int g = 0; g < 4; g++) {
        float4 b = *(const float4*)(bp + 8 * g);
        a[4*g+0] = b.x; a[4*g+1] = b.y; a[4*g+2] = b.z; a[4*g+3] = b.w;
    }
}

// MODE 0: h=v   1: t=relu(v)   2: h+=relu(v)   3: h=relu(h+relu(v))
template<int MODE>
DEVFN void store_h(const f32x16& v, unsigned short* buf, int n0)
{
    const int lane = threadIdx.x & 63;
    const int m = lane & 31;
    const int q = lane >> 5;
    unsigned short* rowp = buf + m * HS + n0 + 4 * q;
#pragma unroll
    for (int g = 0; g < 4; g++) {
        f32x2 r0 = {v[4*g+0], v[4*g+1]};
        f32x2 r1 = {v[4*g+2], v[4*g+3]};
        if (MODE >= 1) { r0 = vmax0(r0); r1 = vmax0(r1); }
        unsigned short* dst = rowp + 8 * g;
        if (MODE >= 2) {
            uint2 old = *(const uint2*)dst;
            r0 += (f32x2){bflo(old.x), bfhi(old.x)};
            r1 += (f32x2){bflo(old.y), bfhi(old.y)};
            if (MODE == 3) { r0 = vmax0(r0); r1 = vmax0(r1); }
        }
        uint2 pk;
        pk.x = pack2(r0.x, r0.y);
        pk.y = pack2(r1.x, r1.y);
        *(uint2*)dst = pk;
    }
}

// ---------------- fused flow kernel: 32 rows per block, 4 waves ----------------
// LDS ~39KB (>=3 blocks/CU by LDS); empirical launch_bounds law on this toolchain:
// arch-VGPR cap = 256 / <second arg> (R3: 4->64; R5: 2->128; R7: 4->64+spill).
// (256,2) -> cap 128, spill-free at this code size (R5 evidence); target steady
// state ~100 arch + 32 AGPR -> 3 blocks/CU = 12 waves/CU, 4-wave barrier groups.
__global__ __launch_bounds__(256, 2) void flow_kernel(
    const float* __restrict__ x_in, const float* __restrict__ scS, const float* __restrict__ scB,
    const float* __restrict__ bin, const float* __restrict__ b1a, const float* __restrict__ b1b,
    const float* __restrict__ b2a, const float* __restrict__ b2b,
    const int* __restrict__ cperm,
    const short* __restrict__ wt, const float* __restrict__ bo_t, const float* __restrict__ sld,
    float* __restrict__ out)
{
    __shared__ __align__(16) unsigned short hS[MROW * HS];   // 16896 B
    __shared__ __align__(16) unsigned short uS[MROW * HS];   // union: mx / t
    __shared__ float xS[MROW * XS];                          // 4224 B
    __shared__ float redS[256];                              // 1024 B

    const int tid = threadIdx.x;
    const int wave = tid >> 6;          // 0..3
    const int lane = tid & 63;
    const int q = lane >> 5;
    const size_t rowbase = (size_t)blockIdx.x * MROW;
    unsigned short* tS  = uS;
    unsigned short* mxS = uS;

#pragma unroll
    for (int i = 0; i < 4; i++) {
        int g = tid + i * 256;          // 32 rows x 32 cols
        xS[(g >> 5) * XS + (g & 31)] = x_in[rowbase * NFEAT + g];
    }
    float ld_acc = 0.0f;
    __syncthreads();

    const int nbase = wave * 64;        // 4 waves x 64 cols = 256
    bf16x8 ring[4][2];                  // weight ring, 32 VGPR

#pragma unroll 1
    for (int l = 0; l < NLAYER; l++) {
        const int par = l & 1;
        const short* wb = wt + (size_t)l * LAYER_E;

        // ---- permute(+affine) via composed perm: in-place, no mid-barrier ----
        {
            int j = tid & 31; int r0 = (tid >> 5) * 4;   // 8 groups x 4 rows
            int cj = cperm[l * 32 + j];
            float sc = scS[l * 32 + j], sh = scB[l * 32 + j];
            int keep = ((j & 1) != par);
#pragma unroll
            for (int r = 0; r < 4; r++) {
                float v = fmaf(xS[(r0 + r) * XS + cj], sc, sh);
                xS[(r0 + r) * XS + cj] = v;
                mxS[(r0 + r) * MXS + j] = keep ? bf16r(v) : (unsigned short)0;
            }
        }
        prefA<2>(wb, 256, nbase, ring);              // W_in A in flight during barrier
        __syncthreads();
        // ---- GEMM1: h = mx @ W_in + b_in ----
        {
            f32x16 acc[2];
            binit(acc[0], bin + l * 256 + nbase);
            binit(acc[1], bin + l * 256 + nbase + 32);
            gemm_run<2, 2>(wb, 256, nbase, mxS, MXS, ring, acc);
            prefA<4>(wb + WIN_E, 256, nbase, ring);       // W1a ring
            store_h<0>(acc[0], hS, nbase);
            store_h<0>(acc[1], hS, nbase + 32);
            __syncthreads();
        }
        // ---- residual block 1 ----
        {
            f32x16 acc[2];
            binit(acc[0], b1a + l * 256 + nbase);
            binit(acc[1], b1a + l * 256 + nbase + 32);
            gemm_run<16, 4>(wb + WIN_E, 256, nbase, hS, HS, ring, acc);
            prefA<4>(wb + WIN_E + WH_E, 256, nbase, ring);    // W1b ring
            store_h<1>(acc[0], tS, nbase);
            store_h<1>(acc[1], tS, nbase + 32);
            __syncthreads();
        }
        {
            f32x16 acc[2];
            binit(acc[0], b1b + l * 256 + nbase);
            binit(acc[1], b1b + l * 256 + nbase + 32);
            gemm_run<16, 4>(wb + WIN_E + WH_E, 256, nbase, tS, HS, ring, acc);
            prefA<4>(wb + WIN_E + 2 * WH_E, 256, nbase, ring);    // W2a ring
            store_h<2>(acc[0], hS, nbase);
            store_h<2>(acc[1], hS, nbase + 32);
            __syncthreads();
        }
        // ---- residual block 2 (+ final relu folded) ----
        {
            f32x16 acc[2];
            binit(acc[0], b2a + l * 256 + nbase);
            binit(acc[1], b2a + l * 256 + nbase + 32);
            gemm_run<16, 4>(wb + WIN_E + 2 * WH_E, 256, nbase, hS, HS, ring, acc);
            prefA<4>(wb + WIN_E + 3 * WH_E, 256, nbase, ring);    // W2b ring
            store_h<1>(acc[0], tS, nbase);
            store_h<1>(acc[1], tS, nbase + 32);
            __syncthreads();
        }
        {
            f32x16 acc[2];
            binit(acc[0], b2b + l * 256 + nbase);
            binit(acc[1], b2b + l * 256 + nbase + 32);
            gemm_run<16, 4>(wb + WIN_E + 3 * WH_E, 256, nbase, tS, HS, ring, acc);
            prefA<2>(wb + WIN_E + 4 * WH_E, 512, wave * 128, ring);   // W_out pass-0
            store_h<3>(acc[0], hS, nbase);
            store_h<3>(acc[1], hS, nbase + 32);
            __syncthreads();
        }
        // ---- W_out: wave w owns cols [128w,128w+128) = features 4w..4w+3 ----
        // 2 passes x 64 cols (= 2 features). acc[0]/acc[1] hold features u0/u1;
        // lane^32 exchange merges param-quarters so lane q ends with the FULL
        // 32-param vector of feature u0 (q=0) or u1 (q=1), row = lane&31.
        {
            const short* wo = wb + WIN_E + 4 * WH_E;
#pragma unroll
            for (int s = 0; s < 2; s++) {
                f32x16 acc[2];
                const float* bb = bo_t + l * 512 + wave * 128 + s * 64;
                binit(acc[0], bb);
                binit(acc[1], bb + 32);
                gemm_run<16, 2>(wo, 512, wave * 128 + s * 64, hS, HS, ring, acc);
                if (s == 0) prefA<2>(wo, 512, wave * 128 + 64, ring);   // pass-1

                float exch[16];
#pragma unroll
                for (int i = 0; i < 16; i++) {
                    float snd = q ? acc[0][i] : acc[1][i];
                    exch[i] = __shfl_xor(snd, 32, 64);
                }
                float A0[16], A1[16];   // param quarters: A0 = n%8 in 0..3, A1 = 4..7
#pragma unroll
                for (int i = 0; i < 16; i++) {
                    float kept = q ? acc[1][i] : acc[0][i];
                    A0[i] = q ? exch[i] : kept;
                    A1[i] = q ? kept : exch[i];
                }
                // slopes n=16..24: n=16+i -> i<4: A0[8+i]; i in 4..7: A1[4+i]; n=24: A0[12]
                float sl[9];
#pragma unroll
                for (int i = 0; i < 4; i++) { sl[i] = A0[8 + i]; sl[4 + i] = A1[8 + i]; }
                sl[8] = A0[12];
                // widths n=i: i<4 A0[i] else A1[i-4]; heights n=8+i: i<4 A0[4+i] else A1[i]
                float w[8], hh[8], sw = 0.f, sh2 = 0.f;
#pragma unroll
                for (int i = 0; i < 8; i++) {
                    w[i] = __expf(i < 4 ? A0[i] : A1[i - 4]);  sw += w[i];
                    hh[i] = __expf(i < 4 ? A0[4 + i] : A1[i]); sh2 += hh[i];
                }
                float fw = WSCALE * frcp(sw), fh = WSCALE * frcp(sh2);
#pragma unroll
                for (int i = 0; i < 8; i++) {
                    w[i] = fmaf(w[i], fw, MIN_BIN);
                    hh[i] = fmaf(hh[i], fh, MIN_BIN);
                }
                // ---- spline for (row = lane&31, feature u = 4*wave + 2*s + q) ----
                int n = 2 * (4 * wave + 2 * s + q) + par;
                int cn = cperm[l * 32 + n];
                float xv = xS[(lane & 31) * XS + cn];

                bool inside = (xv > -10.0f) && (xv < 10.0f);
                float xc = fminf(fmaxf(xv, -10.0f), 10.0f);
                float cx = -10.0f + w[0], cy = -10.0f + hh[0];
                float xk = -10.0f, yk = -10.0f, bw = w[0], bh = hh[0];
                float udk = sl[0], udk1 = sl[1];
#pragma unroll
                for (int i = 1; i < 8; i++) {
                    bool take = (xc >= cx);
                    if (take) { xk = cx; yk = cy; bw = w[i]; bh = hh[i]; udk = sl[i]; udk1 = sl[i + 1]; }
                    cx += w[i]; cy += hh[i];
                }
                float dk  = __logf(1.f + __expf(udk  + SOFTPLUS_OFF)) + MIN_SLOPE;
                float dk1 = __logf(1.f + __expf(udk1 + SOFTPLUS_OFF)) + MIN_SLOPE;
                float ibw = frcp(bw);
                float s_ = bh * ibw;
                float z = fminf(fmaxf((xc - xk) * ibw, 0.0f), 1.0f);
                float omz = 1.0f - z;
                float zz = z * omz;
                float denom = fmaf(dk1 + dk - 2.0f * s_, zz, s_);
                float idenom = frcp(denom);
                float y = fmaf(bh * fmaf(s_ * z, z, dk * zz), idenom, yk);
                float num = fmaf(dk1 * z, z, fmaf(2.0f * s_, zz, dk * omz * omz));
                float t1 = s_ * idenom;                 // ld = log(s^2 * num / denom^2)
                float ldv = __logf(t1 * t1 * num);
                xS[(lane & 31) * XS + cn] = inside ? y : xv;
                ld_acc += inside ? ldv : 0.0f;
            }
            __syncthreads();
        }
    }
    // ---- epilogue: logp + logdet ----
    {
        int m = tid & 31, jg = tid >> 5;    // 8 groups x 4 cols
        float s2 = 0.f;
#pragma unroll
        for (int j = 0; j < 4; j++) { float v = xS[m * XS + jg * 4 + j]; s2 += v * v; }
        redS[tid] = ld_acc - 0.5f * s2;
        __syncthreads();
        if (tid < 32) {
            float tot = *sld - 29.406033062549525f;   // -0.5*N*log(2*pi)
#pragma unroll
            for (int k = 0; k < 8; k++) tot += redS[tid + 32 * k];
            out[rowbase + tid] = tot;
        }
    }
}

extern "C" void kernel_launch(void* const* d_in, const int* in_sizes, int n_in,
                              void* d_out, int out_size, void* d_ws, size_t ws_size,
                              hipStream_t stream) {
    if (ws_size < WS_NEEDED) return;   // scratch too small: fail loudly (poisoned out)
    const float* x    = (const float*)d_in[0];
    const float* scS  = (const float*)d_in[1];
    const float* scB  = (const float*)d_in[2];
    const float* Win  = (const float*)d_in[3];
    const float* bin  = (const float*)d_in[4];
    const float* W1a  = (const float*)d_in[5];
    const float* b1a  = (const float*)d_in[6];
    const float* W1b  = (const float*)d_in[7];
    const float* b1b  = (const float*)d_in[8];
    const float* W2a  = (const float*)d_in[9];
    const float* b2a  = (const float*)d_in[10];
    const float* W2b  = (const float*)d_in[11];
    const float* b2b  = (const float*)d_in[12];
    const float* Wout = (const float*)d_in[13];
    const float* bout = (const float*)d_in[14];
    const int* perms  = (const int*)d_in[15];

    short* wt   = (short*)d_ws;
    float* bo_t = (float*)((char*)d_ws + WT_BYTES);
    float* sld  = bo_t + NLAYER * 512;
    int* cperm  = (int*)((char*)d_ws + CPERM_OFF);

    prep_kernel<<<657, 256, 0, stream>>>(Win, W1a, W1b, W2a, W2b, Wout, bout, scS, perms,
                                         wt, bo_t, sld, cperm);
    flow_kernel<<<65536 / MROW, 256, 0, stream>>>(x, scS, scB, bin, b1a, b1b, b2a, b2b,
                                                  cperm, wt, bo_t, sld, (float*)d_out);
}

// Round 9
// 576.347 us; speedup vs baseline: 1.5878x; 1.5878x over previous
//
#include <hip/hip_runtime.h>
#include <hip/hip_bf16.h>

typedef __attribute__((ext_vector_type(8))) short bf16x8;
typedef __attribute__((ext_vector_type(16))) float f32x16;
typedef __attribute__((ext_vector_type(2))) float f32x2;

#define DEVFN __device__ __forceinline__

constexpr int NFEAT = 32, NLAYER = 8, HID = 256;
constexpr int HS  = 264;   // h/t LDS stride (bf16 elements), 16B-aligned
constexpr int MXS = 40;    // mx LDS stride
constexpr int XS  = 33;    // x LDS stride (floats)
constexpr int WIN_E  = 2 * 256 * 16;    // 8192
constexpr int WH_E   = 16 * 256 * 16;   // 65536
constexpr int WOUT_E = 16 * 512 * 16;   // 131072
constexpr int LAYER_E = WIN_E + 4 * WH_E + WOUT_E;  // 401408 bf16 elems
constexpr size_t WT_BYTES = (size_t)LAYER_E * NLAYER * 2;  // 6422528
constexpr size_t CPERM_OFF = WT_BYTES + (size_t)NLAYER * 512 * 4 + 4;  // bo_t + sld
constexpr size_t WS_NEEDED = CPERM_OFF + (size_t)NLAYER * 32 * 4;

constexpr float MIN_BIN = 1e-4f, MIN_SLOPE = 1e-4f;
constexpr float SOFTPLUS_OFF = 0.5411666f;           // log(expm1(1 - MIN_SLOPE))
constexpr float WSCALE = 20.0f - 8.0f * MIN_BIN;     // (RMAX-RMIN) - K*MIN_BIN

DEVFN unsigned short bf16r(float f) {              // fp32 -> bf16, RNE
    unsigned u = __float_as_uint(f);
    u += 0x7fffu + ((u >> 16) & 1u);
    return (unsigned short)(u >> 16);
}
#if defined(__gfx950__) && __has_builtin(__builtin_amdgcn_cvt_pk_bf16_f32)
DEVFN unsigned pack2(float a, float b) {
    auto r = __builtin_amdgcn_cvt_pk_bf16_f32(a, b);
    return __builtin_bit_cast(unsigned, r);
}
#else
DEVFN unsigned pack2(float a, float b) {
    return (unsigned)bf16r(a) | ((unsigned)bf16r(b) << 16);
}
#endif
DEVFN float bflo(unsigned v) { return __uint_as_float(v << 16); }
DEVFN float bfhi(unsigned v) { return __uint_as_float(v & 0xffff0000u); }
DEVFN float frcp(float x) { return __builtin_amdgcn_rcpf(x); }
DEVFN f32x2 vmax0(f32x2 v) {
#if __has_builtin(__builtin_elementwise_max)
    return __builtin_elementwise_max(v, (f32x2){0.f, 0.f});
#else
    return (f32x2){fmaxf(v.x, 0.f), fmaxf(v.y, 0.f)};
#endif
}

// lane-half exchange: after call, a = [a.lanes0-31 | b.lanes0-31 moved to 32-63],
// b = [a.lanes32-63 moved to 0-31 | b.lanes32-63]. Exactly the A0/A1 gather the
// old shfl_xor(+selects) path computed, in ONE VALU op (T12 primitive, m255).
DEVFN void swap32(float& a, float& b) {
#if defined(__gfx950__) && __has_builtin(__builtin_amdgcn_permlane32_swap)
    auto r = __builtin_amdgcn_permlane32_swap(__float_as_uint(a), __float_as_uint(b), false, false);
    a = __uint_as_float(r[0]);
    b = __uint_as_float(r[1]);
#else
    asm volatile("v_permlane32_swap_b32 %0, %1" : "+v"(a), "+v"(b));
#endif
}

// ---------------- prep kernel: bf16 transposed weight tiles in ws ----------------
// wt layout per matrix: [kstep][n][16kk] with element = W[k=kstep*16+kk][n]
__global__ __launch_bounds__(256) void prep_kernel(
    const float* __restrict__ Win, const float* __restrict__ W1a, const float* __restrict__ W1b,
    const float* __restrict__ W2a, const float* __restrict__ W2b, const float* __restrict__ Wout,
    const float* __restrict__ bout, const float* __restrict__ scS,
    const int* __restrict__ perms,
    short* __restrict__ wt, float* __restrict__ bo_t, float* __restrict__ sld,
    int* __restrict__ cperm)
{
    __shared__ float lb[16 * 800];
    const int b = blockIdx.x, t = threadIdx.x;
    if (b < 16) {                       // W_in: (L,32,256), k-dim = 32 -> 2 ksteps
        int l = b >> 1, ks = b & 1;
        const float* src = Win + l * 32 * 256 + ks * 16 * 256;
#pragma unroll
        for (int i = 0; i < 16; i++) { int idx = t + i * 256; lb[idx] = src[idx]; }
        __syncthreads();
        short* dst = wt + (size_t)l * LAYER_E + ks * 4096;
#pragma unroll
        for (int i = 0; i < 16; i++) {
            int o = t + i * 256; int n = o >> 4, kk = o & 15;
            dst[o] = (short)bf16r(lb[kk * 256 + n]);
        }
    } else if (b < 528) {               // W1a/W1b/W2a/W2b: 256x256, 16 ksteps each
        int id = b - 16; int l = id >> 6, mat = (id >> 4) & 3, ks = id & 15;
        const float* mats[4] = {W1a, W1b, W2a, W2b};
        const float* src = mats[mat] + l * 65536 + ks * 16 * 256;
#pragma unroll
        for (int i = 0; i < 16; i++) { int idx = t + i * 256; lb[idx] = src[idx]; }
        __syncthreads();
        short* dst = wt + (size_t)l * LAYER_E + WIN_E + mat * WH_E + ks * 4096;
#pragma unroll
        for (int i = 0; i < 16; i++) {
            int o = t + i * 256; int n = o >> 4, kk = o & 15;
            dst[o] = (short)bf16r(lb[kk * 256 + n]);
        }
    } else if (b < 656) {               // W_out: trim to unmasked cols, pad 25->32
        int id = b - 528; int l = id >> 4, ks = id & 15; int par = l & 1;
        const float* src = Wout + (size_t)l * 256 * 800 + ks * 16 * 800;
        for (int k = 0; k < 16; k++)
            for (int c = t; c < 800; c += 256) lb[k * 800 + c] = src[k * 800 + c];
        __syncthreads();
        short* dst = wt + (size_t)l * LAYER_E + WIN_E + 4 * WH_E + ks * 8192;
#pragma unroll
        for (int i = 0; i < 32; i++) {
            int o = t + i * 256; int c = o >> 4, kk = o & 15;
            int u = c >> 5, p = c & 31;
            float v = (p < 25) ? lb[kk * 800 + (2 * u + par) * 25 + p] : 0.0f;
            dst[o] = (short)bf16r(v);
        }
    } else {                            // trimmed b_out + scale-logdet + composed perms
        if (t == 0) {                   // C_l = C_{l-1} o P_l  (frame-l feature -> storage col)
            for (int j = 0; j < 32; j++) cperm[j] = perms[j];
            for (int l = 1; l < NLAYER; l++)
                for (int j = 0; j < 32; j++)
                    cperm[l * 32 + j] = cperm[(l - 1) * 32 + perms[l * 32 + j]];
        }
#pragma unroll
        for (int i = 0; i < 16; i++) {
            int idx = t + i * 256;                    // 8 layers * 512
            int l = idx >> 9, c = idx & 511, u = c >> 5, p = c & 31;
            bo_t[idx] = (p < 25) ? bout[l * 800 + (2 * u + (l & 1)) * 25 + p] : 0.0f;
        }
        lb[t] = logf(fabsf(scS[t]));                  // 8*32 = 256 values
        __syncthreads();
        for (int s = 128; s > 0; s >>= 1) { if (t < s) lb[t] += lb[t + s]; __syncthreads(); }
        if (t == 0) *sld = lb[0];
    }
}

// ---------------- flipped GEMM: A = weights (global tiles), B = activations (LDS) ----
// Ring prologue is issued by the CALLER (prefA) before the __syncthreads preceding
// the phase, so weight-load latency hides under the previous phase's epilogue.
template<int D, int NSUB>
DEVFN void prefA(const short* __restrict__ wt, int ntot, int nbase, bf16x8 (&a)[D][NSUB])
{
    const int lane = threadIdx.x & 63;
    const bf16x8* __restrict__ w8 = (const bf16x8*)wt;
    const int wb = (nbase + (lane & 31)) * 2 + (lane >> 5);
    const int krow = ntot * 2;                        // bf16x8 units per kstep row
#pragma unroll
    for (int p = 0; p < D; p++)
#pragma unroll
        for (int s = 0; s < NSUB; s++)
            a[p][s] = w8[(size_t)p * krow + wb + s * 64];
}

template<int KSTEPS, int NSUB, int D>
DEVFN void gemm_run(const short* __restrict__ wt, int ntot, int nbase,
                    const unsigned short* __restrict__ B, int bs,
                    bf16x8 (&a)[D][NSUB], f32x16 (&acc)[NSUB][2])
{
    const int lane = threadIdx.x & 63;
    const int l31 = lane & 31, l5 = lane >> 5;
    const bf16x8* __restrict__ w8 = (const bf16x8*)wt;
    const int wb = (nbase + l31) * 2 + l5;
    const int krow = ntot * 2;
    const unsigned short* bp = B + l31 * bs + l5 * 8;
#pragma unroll
    for (int k = 0; k < KSTEPS; k++) {
        bf16x8 b0 = *(const bf16x8*)(bp + k * 16);
        bf16x8 b1 = *(const bf16x8*)(bp + 32 * bs + k * 16);
#pragma unroll
        for (int s = 0; s < NSUB; s++) {
            acc[s][0] = __builtin_amdgcn_mfma_f32_32x32x16_bf16(a[k % D][s], b0, acc[s][0], 0, 0, 0);
            acc[s][1] = __builtin_amdgcn_mfma_f32_32x32x16_bf16(a[k % D][s], b1, acc[s][1], 0, 0, 0);
        }
        if (k + D < KSTEPS) {
#pragma unroll
            for (int s = 0; s < NSUB; s++) a[k % D][s] = w8[(size_t)(k + D) * krow + wb + s * 64];
        }
    }
}

// acc init from bias (bias pre-added so epilogue is pure pack/store)
// D-layout row = (reg&3) + 8*(reg>>2) + 4*(lane>>5); bias points at column base n0
DEVFN void binit(f32x16& a, const float* __restrict__ bias)
{
    const int q = (threadIdx.x >> 5) & 1;
    const float* bp = bias + 4 * q;
#pragma unroll
    for (int g = 0; g < 4; g++) {
        float4 b = *(const float4*)(bp + 8 * g);
        a[4*g+0] = b.x; a[4*g+1] = b.y; a[4*g+2] = b.z; a[4*g+3] = b.w;
    }
}

// MODE 0: h=v   1: t=relu(v)   2: h+=relu(v)   3: h=relu(h+relu(v))   (bias already in v)
template<int MODE>
DEVFN void store_h(const f32x16& v, unsigned short* buf, int m0, int n0)
{
    const int lane = threadIdx.x & 63;
    const int m = m0 + (lane & 31);
    const int q = lane >> 5;
    unsigned short* rowp = buf + m * HS + n0 + 4 * q;
#pragma unroll
    for (int g = 0; g < 4; g++) {
        f32x2 r0 = {v[4*g+0], v[4*g+1]};
        f32x2 r1 = {v[4*g+2], v[4*g+3]};
        if (MODE >= 1) { r0 = vmax0(r0); r1 = vmax0(r1); }
        unsigned short* dst = rowp + 8 * g;
        if (MODE >= 2) {
            uint2 old = *(const uint2*)dst;
            r0 += (f32x2){bflo(old.x), bfhi(old.x)};
            r1 += (f32x2){bflo(old.y), bfhi(old.y)};
            if (MODE == 3) { r0 = vmax0(r0); r1 = vmax0(r1); }
        }
        uint2 pk;
        pk.x = pack2(r0.x, r0.y);
        pk.y = pack2(r1.x, r1.y);
        *(uint2*)dst = pk;
    }
}

// ---------------- fused flow kernel: 64 rows per block (R2 champion structure) ----
// 256 threads / 4 waves / M=64 / 2 blocks per CU (LDS-bound). This config beat
// every occupancy-raising restructure (R3-R8): per-block MFMA density and
// cross-block barrier overlap matter more than wave count here.
__global__ __launch_bounds__(256, 2) void flow_kernel(
    const float* __restrict__ x_in, const float* __restrict__ scS, const float* __restrict__ scB,
    const float* __restrict__ bin, const float* __restrict__ b1a, const float* __restrict__ b1b,
    const float* __restrict__ b2a, const float* __restrict__ b2b,
    const int* __restrict__ cperm,
    const short* __restrict__ wt, const float* __restrict__ bo_t, const float* __restrict__ sld,
    float* __restrict__ out)
{
    __shared__ __align__(16) unsigned short hS[64 * HS];   // 33792 B
    __shared__ __align__(16) unsigned short uS[64 * HS];   // union: mx / t (33792 B)
    __shared__ float xS[64 * XS];                          // 8448 B
    __shared__ float redS[256];                            // 1024 B

    const int tid = threadIdx.x;
    const int wave = tid >> 6;
    const int lane = tid & 63;
    const size_t rowbase = (size_t)blockIdx.x * 64;
    unsigned short* tS  = uS;
    unsigned short* mxS = uS;

#pragma unroll
    for (int i = 0; i < 8; i++) {
        int g = tid + i * 256;
        xS[(g >> 5) * XS + (g & 31)] = x_in[rowbase * NFEAT + g];
    }
    float ld_acc = 0.0f;
    __syncthreads();

    const int nbase = wave * 64;
    bf16x8 rG1[2][2];      // W_in ring (whole A: 2 ksteps)
    bf16x8 rB[8][2];       // 256x256 ring, D=8 (covers L2-miss/L3 latency), reused x4
    bf16x8 rW[2][4];       // W_out ring, D=2

#pragma unroll 1
    for (int l = 0; l < NLAYER; l++) {
        const int par = l & 1;
        const short* wb = wt + (size_t)l * LAYER_E;

        // ---- permute(+affine) via composed perm: in-place, no mid-barrier ----
        // Thread owns storage column cj = C_l[j]; C is a bijection so no aliasing.
        {
            int j = tid & 31; int r0 = (tid >> 5) * 8;
            int cj = cperm[l * 32 + j];
            float sc = scS[l * 32 + j], sh = scB[l * 32 + j];
            int keep = ((j & 1) != par);   // mask==True features feed the conditioner
#pragma unroll
            for (int r = 0; r < 8; r++) {
                float v = fmaf(xS[(r0 + r) * XS + cj], sc, sh);
                xS[(r0 + r) * XS + cj] = v;
                mxS[(r0 + r) * MXS + j] = keep ? bf16r(v) : (unsigned short)0;
            }
        }
        prefA<2, 2>(wb, 256, nbase, rG1);            // W_in A in flight during barrier
        __syncthreads();
        // ---- GEMM1: h = mx @ W_in + b_in ----
        {
            f32x16 acc[2][2];
            binit(acc[0][0], bin + l * 256 + nbase);      binit(acc[0][1], bin + l * 256 + nbase);
            binit(acc[1][0], bin + l * 256 + nbase + 32); binit(acc[1][1], bin + l * 256 + nbase + 32);
            gemm_run<2, 2, 2>(wb, 256, nbase, mxS, MXS, rG1, acc);
            prefA<8, 2>(wb + WIN_E, 256, nbase, rB);      // W1a ring
#pragma unroll
            for (int s = 0; s < 2; s++) {
                store_h<0>(acc[s][0], hS, 0,  nbase + s * 32);
                store_h<0>(acc[s][1], hS, 32, nbase + s * 32);
            }
            __syncthreads();
        }
        // ---- residual block 1 ----
        {
            f32x16 acc[2][2];
            binit(acc[0][0], b1a + l * 256 + nbase);      binit(acc[0][1], b1a + l * 256 + nbase);
            binit(acc[1][0], b1a + l * 256 + nbase + 32); binit(acc[1][1], b1a + l * 256 + nbase + 32);
            gemm_run<16, 2, 8>(wb + WIN_E, 256, nbase, hS, HS, rB, acc);
            prefA<8, 2>(wb + WIN_E + WH_E, 256, nbase, rB);   // W1b ring
#pragma unroll
            for (int s = 0; s < 2; s++) {
                store_h<1>(acc[s][0], tS, 0,  nbase + s * 32);
                store_h<1>(acc[s][1], tS, 32, nbase + s * 32);
            }
            __syncthreads();
        }
        {
            f32x16 acc[2][2];
            binit(acc[0][0], b1b + l * 256 + nbase);      binit(acc[0][1], b1b + l * 256 + nbase);
            binit(acc[1][0], b1b + l * 256 + nbase + 32); binit(acc[1][1], b1b + l * 256 + nbase + 32);
            gemm_run<16, 2, 8>(wb + WIN_E + WH_E, 256, nbase, tS, HS, rB, acc);
            prefA<8, 2>(wb + WIN_E + 2 * WH_E, 256, nbase, rB);   // W2a ring
#pragma unroll
            for (int s = 0; s < 2; s++) {
                store_h<2>(acc[s][0], hS, 0,  nbase + s * 32);
                store_h<2>(acc[s][1], hS, 32, nbase + s * 32);
            }
            __syncthreads();
        }
        // ---- residual block 2 (+ final relu folded) ----
        {
            f32x16 acc[2][2];
            binit(acc[0][0], b2a + l * 256 + nbase);      binit(acc[0][1], b2a + l * 256 + nbase);
            binit(acc[1][0], b2a + l * 256 + nbase + 32); binit(acc[1][1], b2a + l * 256 + nbase + 32);
            gemm_run<16, 2, 8>(wb + WIN_E + 2 * WH_E, 256, nbase, hS, HS, rB, acc);
            prefA<8, 2>(wb + WIN_E + 3 * WH_E, 256, nbase, rB);   // W2b ring
#pragma unroll
            for (int s = 0; s < 2; s++) {
                store_h<1>(acc[s][0], tS, 0,  nbase + s * 32);
                store_h<1>(acc[s][1], tS, 32, nbase + s * 32);
            }
            __syncthreads();
        }
        {
            f32x16 acc[2][2];
            binit(acc[0][0], b2b + l * 256 + nbase);      binit(acc[0][1], b2b + l * 256 + nbase);
            binit(acc[1][0], b2b + l * 256 + nbase + 32); binit(acc[1][1], b2b + l * 256 + nbase + 32);
            gemm_run<16, 2, 8>(wb + WIN_E + 3 * WH_E, 256, nbase, tS, HS, rB, acc);
            prefA<2, 4>(wb + WIN_E + 4 * WH_E, 512, wave * 128, rW);   // W_out ring
#pragma unroll
            for (int s = 0; s < 2; s++) {
                store_h<3>(acc[s][0], hS, 0,  nbase + s * 32);
                store_h<3>(acc[s][1], hS, 32, nbase + s * 32);
            }
            __syncthreads();
        }
        // ---- W_out single pass: wave w owns cols [128w,128w+128) = features 4w..4w+3 ----
        // permlane32_swap merges the two m-half accumulators into A0/A1 param-halves
        // in ONE op per register pair (replaces shfl_xor + 4 selects); spline params
        // are then indexed directly from A0/A1 (P[p]: half=(p>>2)&1, rg=(p&3)+4*(p>>3)).
        {
            const short* wo = wb + WIN_E + 4 * WH_E;
            f32x16 acc[4][2];
            const float* bb = bo_t + l * 512 + wave * 128;
#pragma unroll
            for (int s = 0; s < 4; s++) { binit(acc[s][0], bb + s * 32); binit(acc[s][1], bb + s * 32); }
            gemm_run<16, 4, 2>(wo, 512, wave * 128, hS, HS, rW, acc);

#pragma unroll
            for (int s = 0; s < 4; s++) {
                float A0[16], A1[16];   // A0 = param-offset {0-3,8-11,16-19,24-27}, A1 = +4
#pragma unroll
                for (int i = 0; i < 16; i++) {
                    float a = acc[s][0][i], b = acc[s][1][i];
                    swap32(a, b);
                    A0[i] = a; A1[i] = b;
                }
                // slopes p=16..24
                float sl[9];
#pragma unroll
                for (int i = 0; i < 4; i++) { sl[i] = A0[8 + i]; sl[4 + i] = A1[8 + i]; }
                sl[8] = A0[12];
                // widths p=0..7, heights p=8..15 (exp applied in place)
                float w[8], hh[8], sw = 0.f, sh2 = 0.f;
#pragma unroll
                for (int i = 0; i < 8; i++) {
                    w[i]  = __expf(i < 4 ? A0[i]     : A1[i - 4]); sw  += w[i];
                    hh[i] = __expf(i < 4 ? A0[4 + i] : A1[i]);     sh2 += hh[i];
                }
                float fw = WSCALE * frcp(sw), fh = WSCALE * frcp(sh2);
#pragma unroll
                for (int i = 0; i < 8; i++) {
                    w[i]  = fmaf(w[i],  fw, MIN_BIN);
                    hh[i] = fmaf(hh[i], fh, MIN_BIN);
                }
                // ---- spline for (row = lane, unmasked feature u = 4*wave + s) ----
                int n = 2 * (4 * wave + s) + par;
                int cn = cperm[l * 32 + n];            // storage column of feature n
                float xv = xS[lane * XS + cn];

                bool inside = (xv > -10.0f) && (xv < 10.0f);
                float xc = fminf(fmaxf(xv, -10.0f), 10.0f);
                float cx = -10.0f + w[0], cy = -10.0f + hh[0];
                float xk = -10.0f, yk = -10.0f, bw = w[0], bh = hh[0];
                float udk = sl[0], udk1 = sl[1];
#pragma unroll
                for (int i = 1; i < 8; i++) {
                    bool take = (xc >= cx);
                    if (take) { xk = cx; yk = cy; bw = w[i]; bh = hh[i]; udk = sl[i]; udk1 = sl[i + 1]; }
                    cx += w[i]; cy += hh[i];
                }
                float dk  = __logf(1.f + __expf(udk  + SOFTPLUS_OFF)) + MIN_SLOPE;
                float dk1 = __logf(1.f + __expf(udk1 + SOFTPLUS_OFF)) + MIN_SLOPE;
                float ibw = frcp(bw);
                float s_ = bh * ibw;
                float z = fminf(fmaxf((xc - xk) * ibw, 0.0f), 1.0f);
                float omz = 1.0f - z;
                float zz = z * omz;
                float denom = fmaf(dk1 + dk - 2.0f * s_, zz, s_);
                float idenom = frcp(denom);
                float y = fmaf(bh * fmaf(s_ * z, z, dk * zz), idenom, yk);
                float num = fmaf(dk1 * z, z, fmaf(2.0f * s_, zz, dk * omz * omz));
                float t1 = s_ * idenom;                 // ld = log(s^2 * num / denom^2)
                float ldv = __logf(t1 * t1 * num);
                xS[lane * XS + cn] = inside ? y : xv;
                ld_acc += inside ? ldv : 0.0f;
            }
            __syncthreads();
        }
    }
    // ---- epilogue: logp + logdet ----
    {
        int m = tid & 63, jg = tid >> 6;
        float s2 = 0.f;
#pragma unroll
        for (int j = 0; j < 8; j++) { float v = xS[m * XS + jg * 8 + j]; s2 += v * v; }
        redS[tid] = ld_acc - 0.5f * s2;
        __syncthreads();
        if (tid < 64) {
            float tot = redS[tid] + redS[tid + 64] + redS[tid + 128] + redS[tid + 192]
                      + *sld - 29.406033062549525f;   // -0.5*N*log(2*pi)
            out[rowbase + tid] = tot;
        }
    }
}

extern "C" void kernel_launch(void* const* d_in, const int* in_sizes, int n_in,
                              void* d_out, int out_size, void* d_ws, size_t ws_size,
                              hipStream_t stream) {
    if (ws_size < WS_NEEDED) return;   // scratch too small: fail loudly (poisoned out)
    const float* x    = (const float*)d_in[0];
    const float* scS  = (const float*)d_in[1];
    const float* scB  = (const float*)d_in[2];
    const float* Win  = (const float*)d_in[3];
    const float* bin  = (const float*)d_in[4];
    const float* W1a  = (const float*)d_in[5];
    const float* b1a  = (const float*)d_in[6];
    const float* W1b  = (const float*)d_in[7];
    const float* b1b  = (const float*)d_in[8];
    const float* W2a  = (const float*)d_in[9];
    const float* b2a  = (const float*)d_in[10];
    const float* W2b  = (const float*)d_in[11];
    const float* b2b  = (const float*)d_in[12];
    const float* Wout = (const float*)d_in[13];
    const float* bout = (const float*)d_in[14];
    const int* perms  = (const int*)d_in[15];

    short* wt   = (short*)d_ws;
    float* bo_t = (float*)((char*)d_ws + WT_BYTES);
    float* sld  = bo_t + NLAYER * 512;
    int* cperm  = (int*)((char*)d_ws + CPERM_OFF);

    prep_kernel<<<657, 256, 0, stream>>>(Win, W1a, W1b, W2a, W2b, Wout, bout, scS, perms,
                                         wt, bo_t, sld, cperm);
    flow_kernel<<<65536 / 64, 256, 0, stream>>>(x, scS, scB, bin, b1a, b1b, b2a, b2b,
                                                cperm, wt, bo_t, sld, (float*)d_out);
}